// Round 9
// baseline (195.944 us; speedup 1.0000x reference)
//
#include <hip/hip_runtime.h>
#include <hip/hip_bf16.h>
#include <math.h>

#define BB 2
#define AA 120000
#define CC 80
#define K_PRE 500
#define MAX_DET 300
#define CAP 2048
#define NB2 256                       // score bins (cold rebuild only)
#define SPEC_BIN 254                  // speculative stage threshold (bin)
#define HB 1200                       // fused blocks (600 per image)
#define QPB 4000                      // quads per block (= 200 anchors * 20)
#define APB 200                       // anchors per block
#define LBUF_G 512                    // LDS spec staging (exp ~118/blk, 30 sigma)

// ---------------- workspace layout (bytes) — base region only -------------
#define OFF_BOXES   0
#define OFF_VALID   3840000
#define OFF_CNT     4161920           // 160 u32 = 640 B, zeroed via memsetAsync
#define OFF_CAND    4163200           // 160*2048*8 = 2,621,440 -> end 6,784,640
// k_sort writes compacted outputs INTO its own (b,c) cand slot (16 KB):
//   words [0,1024) = 512 float4 boxes; [1024,1280) = 512 float scores; [1280] = nv.

// ---------------- K1: fused decode + threshold scan + LDS-staged gather ---
// (byte-identical to the round-8 proven kernel)
__global__ __launch_bounds__(256) void k_fused(
    const float* __restrict__ deltas, const float* __restrict__ anchors,
    const float* __restrict__ scores,
    const int* __restrict__ ih, const int* __restrict__ iw,
    float* __restrict__ boxes, unsigned char* __restrict__ valid,
    unsigned int* __restrict__ cnt, unsigned long long* __restrict__ cand)
{
    __shared__ unsigned char lvalid[APB];
    __shared__ unsigned long long lkey[LBUF_G];   // 4 KB
    __shared__ unsigned short lcls[LBUF_G];       // 1 KB
    __shared__ unsigned int lcnt[CC];
    __shared__ unsigned int lbase[CC];
    __shared__ unsigned int ltot;

    int blk   = blockIdx.x;
    int b     = blk / (HB / BB);
    int abase = blk * APB;
    int start = blk * QPB;
    int end   = start + QPB;

    if (threadIdx.x < CC) lcnt[threadIdx.x] = 0u;
    if (threadIdx.x == 0) ltot = 0u;

    // ---- phase 1: decode this block's anchors ----
    if (threadIdx.x < APB) {
        int a = abase + threadIdx.x;
        float4 d  = ((const float4*)deltas)[a];
        float4 an = ((const float4*)anchors)[a];

        const float CLAMPF = (float)4.135166556742356;  // float(log(1000/16))
        double W = (double)(*iw);
        double H = (double)(*ih);

        double aw  = (double)an.z - (double)an.x;
        double ah  = (double)an.w - (double)an.y;
        double acx = (double)an.x + 0.5 * aw;
        double acy = (double)an.y + 0.5 * ah;

        double dw = fmin((double)d.z, (double)CLAMPF);
        double dh = fmin((double)d.w, (double)CLAMPF);

        double pcx = (double)d.x * aw + acx;
        double pcy = (double)d.y * ah + acy;
        double pw  = exp(dw) * aw;
        double ph  = exp(dh) * ah;

        float x1 = (float)fmin(fmax(pcx - 0.5 * pw, 0.0), W);
        float y1 = (float)fmin(fmax(pcy - 0.5 * ph, 0.0), H);
        float x2 = (float)fmin(fmax(pcx + 0.5 * pw, 0.0), W);
        float y2 = (float)fmin(fmax(pcy + 0.5 * ph, 0.0), H);

        float4 bb; bb.x = x1; bb.y = y1; bb.z = x2; bb.w = y2;
        ((float4*)boxes)[a] = bb;
        unsigned char v = (((x2 - x1) >= 0.01f) && ((y2 - y1) >= 0.01f)) ? 1 : 0;
        valid[a] = v;
        lvalid[threadIdx.x] = v;
    }
    __syncthreads();

    // ---- phase 2: threshold scan (pure-VGPR compare hot loop) ----
    const float4* s4 = (const float4*)scores;
    const float THRF = (float)SPEC_BIN;    // bn >= SPEC_BIN  <=>  sc*256 >= THRF

    for (int i0 = start + threadIdx.x; i0 < end; i0 += 256 * 8) {
        int   ids[8];
        bool  has[8];
        float4 s[8];
        #pragma unroll
        for (int u = 0; u < 8; ++u) {
            int id = i0 + u * 256;
            has[u] = id < end;
            ids[u] = has[u] ? id : start;
        }
        #pragma unroll
        for (int u = 0; u < 8; ++u) s[u] = s4[ids[u]];
        #pragma unroll
        for (int u = 0; u < 8; ++u) {
            if (!has[u]) continue;
            float4 sv = s[u];
            float mx = fmaxf(fmaxf(sv.x, sv.y), fmaxf(sv.z, sv.w));
            if (mx * 256.0f >= THRF) {                 // rare (~4.7% of quads)
                int rel = ids[u] - start;
                int la  = rel / 20;
                if (lvalid[la]) {
                    int q = rel % 20;
                    unsigned int ai = (unsigned int)(abase + la - b * AA);
                    unsigned long long lokey = (unsigned long long)(~ai);
                    float cv[4] = {sv.x, sv.y, sv.z, sv.w};
                    #pragma unroll
                    for (int cl = 0; cl < 4; ++cl) {
                        float sc = cv[cl];
                        if (sc * 256.0f >= THRF) {
                            int c = 4 * q + cl;
                            unsigned long long key =
                                (((unsigned long long)__float_as_uint(sc)) << 32) | lokey;
                            unsigned int p = atomicAdd(&ltot, 1u);
                            if (p < LBUF_G) {
                                lkey[p] = key;
                                lcls[p] = (unsigned short)c;
                                atomicAdd(&lcnt[c], 1u);
                            } else {   // exactness spill (never taken here)
                                unsigned int pos = atomicAdd(&cnt[b * CC + c], 1u);
                                if (pos < CAP)
                                    cand[((size_t)(b * CC + c)) * CAP + pos] = key;
                            }
                        }
                    }
                }
            }
        }
    }
    __syncthreads();

    // ---- flush: one global reservation per class per block ----
    if (threadIdx.x < CC) {
        unsigned int nn = lcnt[threadIdx.x];
        if (nn) lbase[threadIdx.x] = atomicAdd(&cnt[b * CC + threadIdx.x], nn);
    }
    __syncthreads();

    unsigned int tot = min(ltot, (unsigned int)LBUF_G);
    for (unsigned int t = threadIdx.x; t < tot; t += 256) {
        int c = lcls[t];
        unsigned int pos = atomicAdd(&lbase[c], 1u);
        if (pos < CAP)
            cand[((size_t)(b * CC + c)) * CAP + pos] = lkey[t];
    }
}

// ---------------- K2: cold rebuild + bitonic sort + in-slot compact -------
// Diagnostic split of round-8's k_nms2 front half (logic byte-equivalent;
// the in-slot output pattern is round-5-proven). Gives this phase its own
// rocprof row to locate the 2.3x model-vs-measured gap.
__global__ __launch_bounds__(1024) void k_sort(
    const float* __restrict__ boxes, const float* __restrict__ scores,
    const unsigned char* __restrict__ valid,
    const unsigned int* __restrict__ cnt, unsigned long long* __restrict__ cand)
{
    __shared__ unsigned long long kb[2][2048];   // 32 KB double buffer
    __shared__ unsigned int lh32[NB2];           // 1 KB (cold path only)
    __shared__ int best;
    __shared__ unsigned int lpos;

    int bc = blockIdx.x;
    int b  = bc / CC;
    int c  = bc % CC;
    int i  = threadIdx.x;
    unsigned long long* cp = cand + (size_t)bc * CAP;

    int n = (int)cnt[bc];    // attempt count: may exceed CAP
    if (n < K_PRE || n > CAP) {
        // ---- cold rebuild: hist -> cut -> fresh gather (never on this data)
        for (int t = i; t < NB2; t += 1024) lh32[t] = 0u;
        if (i == 0) { best = 0; lpos = 0u; }
        __syncthreads();
        for (int a = i; a < AA; a += 1024) {
            if (valid[b * AA + a]) {
                float sc = scores[((size_t)(b * AA + a)) * CC + c];
                if (sc > 0.05f) {
                    int bn = min((int)(sc * 256.0f), 255);
                    atomicAdd(&lh32[bn], 1u);
                }
            }
        }
        __syncthreads();
        if (i < NB2) {
            unsigned int s = 0;
            for (int j = i; j < NB2; ++j) s += lh32[j];   // suffix sum at i
            if (s >= K_PRE) atomicMax(&best, i);
        }
        __syncthreads();
        int cut = best;
        for (int a = i; a < AA; a += 1024) {
            if (valid[b * AA + a]) {
                float sc = scores[((size_t)(b * AA + a)) * CC + c];
                if (sc > 0.05f) {
                    int bn = min((int)(sc * 256.0f), 255);
                    if (bn >= cut) {
                        unsigned int p = atomicAdd(&lpos, 1u);
                        if (p < CAP)
                            cp[p] = (((unsigned long long)__float_as_uint(sc)) << 32)
                                    | (unsigned long long)(~(unsigned int)a);
                    }
                }
            }
        }
        __syncthreads();   // this block's global writes visible block-wide
        n = (int)min(lpos, (unsigned int)CAP);
    }

    unsigned long long key;

    if (n <= 1024) {
        key = (i < n) ? cp[i] : 0ull;
        int p = 0;
        for (unsigned int k = 2; k <= 1024; k <<= 1) {
            bool up = ((i & k) == 0);
            for (unsigned int j = k >> 1; j > 0; j >>= 1) {
                unsigned long long other;
                if (j >= 64) {
                    kb[p][i] = key;
                    __syncthreads();
                    other = kb[p][i ^ j];
                    p ^= 1;                      // ping-pong: WAR-safe, 1 barrier/pass
                } else {
                    other = __shfl_xor(key, (int)j);
                }
                bool lower = ((i & j) == 0);
                bool keep_max = (lower == up);   // descending in "up" region
                bool mine_big = key > other;
                key = (keep_max == mine_big) ? key : other;
            }
        }
    } else {
        // 2048 fallback: 2 elements/thread (t=i and t=i+1024), hybrid passes
        unsigned long long kA = (i < n) ? cp[i] : 0ull;
        unsigned long long kB = (i + 1024 < n) ? cp[i + 1024] : 0ull;
        int tA = i, tB = i + 1024;
        int p = 0;
        for (unsigned int k = 2; k <= 2048; k <<= 1) {
            for (unsigned int j = k >> 1; j > 0; j >>= 1) {
                if (j == 1024) {
                    // partner is own pair; k=2048 => up=true, tA lower => keep max
                    unsigned long long mx = (kA > kB) ? kA : kB;
                    unsigned long long mn = (kA > kB) ? kB : kA;
                    kA = mx; kB = mn;
                } else if (j >= 64) {
                    kb[p][tA] = kA; kb[p][tB] = kB;
                    __syncthreads();
                    unsigned long long oA = kb[p][tA ^ (int)j];
                    unsigned long long oB = kb[p][tB ^ (int)j];
                    p ^= 1;
                    { bool up = ((tA & k) == 0), lo = ((tA & j) == 0);
                      bool km = (lo == up), mb = kA > oA; kA = (km == mb) ? kA : oA; }
                    { bool up = ((tB & k) == 0), lo = ((tB & j) == 0);
                      bool km = (lo == up), mb = kB > oB; kB = (km == mb) ? kB : oB; }
                } else {
                    unsigned long long oA = __shfl_xor(kA, (int)j);
                    unsigned long long oB = __shfl_xor(kB, (int)j);
                    { bool up = ((tA & k) == 0), lo = ((tA & j) == 0);
                      bool km = (lo == up), mb = kA > oA; kA = (km == mb) ? kA : oA; }
                    { bool up = ((tB & k) == 0), lo = ((tB & j) == 0);
                      bool km = (lo == up), mb = kB > oB; kB = (km == mb) ? kB : oB; }
                }
            }
        }
        key = kA;   // element i (descending) lives in kA across threads
    }

    // ---- compacted in-slot write (reads all precede the last sort barrier)
    float4* sbox = (float4*)cp;            // words [0, 1024)
    float*  ssc  = (float*)(cp + 1024);    // words [1024, 1280)
    int*    nvp  = (int*)(cp + 1280);
    if (i < 512) {
        bool v = (key != 0ull);
        float sc = v ? __uint_as_float((unsigned int)(key >> 32)) : -1.0f;
        int a = v ? (int)(~(unsigned int)key) : 0;
        float4 bb = make_float4(0.f, 0.f, 0.f, 0.f);
        if (v && i < K_PRE) bb = ((const float4*)boxes)[(size_t)b * AA + a];
        sbox[i] = bb;
        ssc[i] = sc;
    }
    if (i == 0) nvp[0] = min(n, K_PRE);
}

// ---------------- K3: mask + greedy + output (8 waves) --------------------
// Round-8 back half: division-free triangular mask into LDS supT, exact
// word-blocked greedy, compaction. 512 threads: same total mask VALU
// (8 waves x 2x iterations), half the barrier/idle-wave overhead.
__global__ __launch_bounds__(512) void k_mg(
    const unsigned long long* __restrict__ cand, float* __restrict__ out)
{
    __shared__ float4 box4[512];                    // 8 KB
    __shared__ float  ar[512];                      // 2 KB
    __shared__ float  scs[512];                     // 2 KB
    __shared__ unsigned long long supT[512 * 9];    // 36 KB (+1 pad: 4-way banks)
    __shared__ unsigned long long keepsh[8];
    __shared__ int pfx[9];

    int bc = blockIdx.x;
    int tid = threadIdx.x;
    const unsigned long long* cp = cand + (size_t)bc * CAP;

    float4 bl = ((const float4*)cp)[tid];           // coalesced slot read
    box4[tid] = bl;
    ar[tid]   = (bl.z - bl.x) * (bl.w - bl.y);
    scs[tid]  = ((const float*)(cp + 1024))[tid];
    int nv    = ((const int*)(cp + 1280))[0];
    __syncthreads();

    // ---- 8-wave triangular mask, LDS-resident supT, division-free -------
    {
        int wave = tid >> 6;
        int lane = tid & 63;
        for (int iw = 0; iw < 8; ++iw) {
            int ii = iw * 64 + lane;
            float4 bi = box4[ii];
            float ia = ar[ii];
            for (int j = iw * 64 + wave; j < nv; j += 8) {
                float4 bj = box4[j];    // wave-uniform broadcast
                float ja = ar[j];       // broadcast
                bool p = false;
                if (ii < j) {
                    float ltx = fmaxf(bi.x, bj.x);
                    float lty = fmaxf(bi.y, bj.y);
                    float rbx = fminf(bi.z, bj.z);
                    float rby = fminf(bi.w, bj.w);
                    float wx = fmaxf(rbx - ltx, 0.0f);
                    float wy = fmaxf(rby - lty, 0.0f);
                    float inter = wx * wy;
                    float den = fmaxf(ia + ja - inter, 1e-9f);
                    float h   = 0.5f * den;          // exact (exponent decrement)
                    float diff = inter - h;          // exact near boundary (Sterbenz)
                    if (fabsf(diff) > h * 9.5367431640625e-07f) {
                        p = diff > 0.0f;             // provably == (inter/den > 0.5)
                    } else {
                        p = (inter / den) > 0.5f;    // vanishing band: replay division
                    }
                }
                unsigned long long m = __ballot(p);
                if (lane == 0) supT[j * 9 + iw] = m;
            }
        }
    }
    __syncthreads();

    int nvv = nv;

    // ---- exact greedy: word-blocked Gauss-Seidel, intra-word Jacobi ----
    if (tid < 64) {
        int l = tid;
        unsigned long long kept[8];
        #pragma unroll
        for (int w = 0; w < 8; ++w) {
            int j = w * 64 + l;
            bool vj = j < nvv;
            bool ext = false;
            #pragma unroll
            for (int w2 = 0; w2 < 8; ++w2)
                if (w2 < w) ext = ext || (vj && (supT[j * 9 + w2] & kept[w2]) != 0ull);
            unsigned long long intra = vj ? supT[j * 9 + w] : 0ull;  // bits i<j only
            bool base = vj && !ext;
            unsigned long long kw = __ballot(base);
            for (int r = 0; r < 64; ++r) {                // depth <= 64 => exact
                bool k2 = base && ((intra & kw) == 0ull);
                unsigned long long nkw = __ballot(k2);
                if (nkw == kw) break;
                kw = nkw;
            }
            kept[w] = kw;
        }
        if (l < 8) keepsh[l] = kept[l];
    }
    __syncthreads();

    if (tid == 0) {
        int s = 0;
        for (int w = 0; w < 8; ++w) { pfx[w] = s; s += __popcll(keepsh[w]); }
        pfx[8] = s;
    }
    __syncthreads();

    // ---- compaction: kept first (score order), then non-kept ----
    int total_kept = pfx[8];
    if (tid < K_PRE) {
        int t = tid;
        int w = t >> 6, bit = t & 63;
        unsigned long long kw = keepsh[w];
        bool kv = (kw >> bit) & 1ull;
        int kb2 = pfx[w] + __popcll(kw & ((bit == 0) ? 0ull : ((1ull << bit) - 1ull)));
        int p = kv ? kb2 : (total_kept + (t - kb2));
        if (p < MAX_DET) {
            float* o = out + ((size_t)bc * MAX_DET + p) * 5;
            if (kv) {
                float4 bb = box4[t];
                o[0] = bb.x; o[1] = bb.y; o[2] = bb.z; o[3] = bb.w; o[4] = scs[t];
            } else {
                o[0] = 0.f; o[1] = 0.f; o[2] = 0.f; o[3] = 0.f; o[4] = -1.0f;
            }
        }
    }
}

extern "C" void kernel_launch(void* const* d_in, const int* in_sizes, int n_in,
                              void* d_out, int out_size, void* d_ws, size_t ws_size,
                              hipStream_t stream)
{
    const float* deltas  = (const float*)d_in[0];
    const float* scores  = (const float*)d_in[1];
    const float* anchors = (const float*)d_in[2];
    const int*   ih      = (const int*)d_in[3];
    const int*   iw      = (const int*)d_in[4];
    float* out = (float*)d_out;

    char* w = (char*)d_ws;
    float*              boxes  = (float*)(w + OFF_BOXES);
    unsigned char*      valid  = (unsigned char*)(w + OFF_VALID);
    unsigned int*       cnt    = (unsigned int*)(w + OFF_CNT);
    unsigned long long* cand   = (unsigned long long*)(w + OFF_CAND);

    hipMemsetAsync(cnt, 0, BB * CC * sizeof(unsigned int), stream);
    k_fused<<<HB, 256, 0, stream>>>(deltas, anchors, scores, ih, iw,
                                    boxes, valid, cnt, cand);
    k_sort<<<BB * CC, 1024, 0, stream>>>(boxes, scores, valid, cnt, cand);
    k_mg<<<BB * CC, 512, 0, stream>>>(cand, out);
}

// Round 10
// 166.928 us; speedup vs baseline: 1.1738x; 1.1738x over previous
//
#include <hip/hip_runtime.h>
#include <hip/hip_bf16.h>
#include <math.h>

#define BB 2
#define AA 120000
#define CC 80
#define K_PRE 500
#define MAX_DET 300
#define CAP 2048
#define NB2 256                       // score bins (cold rebuild only)
#define SPEC_BIN 254                  // speculative stage threshold (bin)
#define HB 1200                       // fused blocks (600 per image)
#define QPB 4000                      // quads per block (= 200 anchors * 20)
#define APB 200                       // anchors per block
#define LBUF_G 512                    // LDS spec staging (exp ~118/blk, 30 sigma)

// ---------------- workspace layout (bytes) — base region only -------------
#define OFF_BOXES   0
#define OFF_VALID   3840000
#define OFF_CNT     4161920           // 160 u32 = 640 B, zeroed via memsetAsync
#define OFF_CAND    4163200           // 160*2048*8 = 2,621,440 -> end 6,784,640

// ---------------- K1: fused decode + threshold scan + LDS-staged gather ---
// (byte-identical to the round-8 proven kernel)
__global__ __launch_bounds__(256) void k_fused(
    const float* __restrict__ deltas, const float* __restrict__ anchors,
    const float* __restrict__ scores,
    const int* __restrict__ ih, const int* __restrict__ iw,
    float* __restrict__ boxes, unsigned char* __restrict__ valid,
    unsigned int* __restrict__ cnt, unsigned long long* __restrict__ cand)
{
    __shared__ unsigned char lvalid[APB];
    __shared__ unsigned long long lkey[LBUF_G];   // 4 KB
    __shared__ unsigned short lcls[LBUF_G];       // 1 KB
    __shared__ unsigned int lcnt[CC];
    __shared__ unsigned int lbase[CC];
    __shared__ unsigned int ltot;

    int blk   = blockIdx.x;
    int b     = blk / (HB / BB);
    int abase = blk * APB;
    int start = blk * QPB;
    int end   = start + QPB;

    if (threadIdx.x < CC) lcnt[threadIdx.x] = 0u;
    if (threadIdx.x == 0) ltot = 0u;

    // ---- phase 1: decode this block's anchors ----
    if (threadIdx.x < APB) {
        int a = abase + threadIdx.x;
        float4 d  = ((const float4*)deltas)[a];
        float4 an = ((const float4*)anchors)[a];

        const float CLAMPF = (float)4.135166556742356;  // float(log(1000/16))
        double W = (double)(*iw);
        double H = (double)(*ih);

        double aw  = (double)an.z - (double)an.x;
        double ah  = (double)an.w - (double)an.y;
        double acx = (double)an.x + 0.5 * aw;
        double acy = (double)an.y + 0.5 * ah;

        double dw = fmin((double)d.z, (double)CLAMPF);
        double dh = fmin((double)d.w, (double)CLAMPF);

        double pcx = (double)d.x * aw + acx;
        double pcy = (double)d.y * ah + acy;
        double pw  = exp(dw) * aw;
        double ph  = exp(dh) * ah;

        float x1 = (float)fmin(fmax(pcx - 0.5 * pw, 0.0), W);
        float y1 = (float)fmin(fmax(pcy - 0.5 * ph, 0.0), H);
        float x2 = (float)fmin(fmax(pcx + 0.5 * pw, 0.0), W);
        float y2 = (float)fmin(fmax(pcy + 0.5 * ph, 0.0), H);

        float4 bb; bb.x = x1; bb.y = y1; bb.z = x2; bb.w = y2;
        ((float4*)boxes)[a] = bb;
        unsigned char v = (((x2 - x1) >= 0.01f) && ((y2 - y1) >= 0.01f)) ? 1 : 0;
        valid[a] = v;
        lvalid[threadIdx.x] = v;
    }
    __syncthreads();

    // ---- phase 2: threshold scan (pure-VGPR compare hot loop) ----
    const float4* s4 = (const float4*)scores;
    const float THRF = (float)SPEC_BIN;    // bn >= SPEC_BIN  <=>  sc*256 >= THRF

    for (int i0 = start + threadIdx.x; i0 < end; i0 += 256 * 8) {
        int   ids[8];
        bool  has[8];
        float4 s[8];
        #pragma unroll
        for (int u = 0; u < 8; ++u) {
            int id = i0 + u * 256;
            has[u] = id < end;
            ids[u] = has[u] ? id : start;
        }
        #pragma unroll
        for (int u = 0; u < 8; ++u) s[u] = s4[ids[u]];
        #pragma unroll
        for (int u = 0; u < 8; ++u) {
            if (!has[u]) continue;
            float4 sv = s[u];
            float mx = fmaxf(fmaxf(sv.x, sv.y), fmaxf(sv.z, sv.w));
            if (mx * 256.0f >= THRF) {                 // rare (~4.7% of quads)
                int rel = ids[u] - start;
                int la  = rel / 20;
                if (lvalid[la]) {
                    int q = rel % 20;
                    unsigned int ai = (unsigned int)(abase + la - b * AA);
                    unsigned long long lokey = (unsigned long long)(~ai);
                    float cv[4] = {sv.x, sv.y, sv.z, sv.w};
                    #pragma unroll
                    for (int cl = 0; cl < 4; ++cl) {
                        float sc = cv[cl];
                        if (sc * 256.0f >= THRF) {
                            int c = 4 * q + cl;
                            unsigned long long key =
                                (((unsigned long long)__float_as_uint(sc)) << 32) | lokey;
                            unsigned int p = atomicAdd(&ltot, 1u);
                            if (p < LBUF_G) {
                                lkey[p] = key;
                                lcls[p] = (unsigned short)c;
                                atomicAdd(&lcnt[c], 1u);
                            } else {   // exactness spill (never taken here)
                                unsigned int pos = atomicAdd(&cnt[b * CC + c], 1u);
                                if (pos < CAP)
                                    cand[((size_t)(b * CC + c)) * CAP + pos] = key;
                            }
                        }
                    }
                }
            }
        }
    }
    __syncthreads();

    // ---- flush: one global reservation per class per block ----
    if (threadIdx.x < CC) {
        unsigned int nn = lcnt[threadIdx.x];
        if (nn) lbase[threadIdx.x] = atomicAdd(&cnt[b * CC + threadIdx.x], nn);
    }
    __syncthreads();

    unsigned int tot = min(ltot, (unsigned int)LBUF_G);
    for (unsigned int t = threadIdx.x; t < tot; t += 256) {
        int c = lcls[t];
        unsigned int pos = atomicAdd(&lbase[c], 1u);
        if (pos < CAP)
            cand[((size_t)(b * CC + c)) * CAP + pos] = lkey[t];
    }
}

// ---------------- K2: rebuild + sort + word-mask + greedy + output --------
// Re-fused (round-9 split was diagnostic; k_mg showed mask+greedy is the
// cost and is LATENCY-bound). New mask: one thread owns one 64-bit supT
// word — 64 IoUs vs a wave-uniform broadcast column accumulate into a
// register, ONE ds_write per word. No ballot, no exec dance, no per-
// iteration read/write interleave (the lgkmcnt serializer). Bitwise-
// identical bits to the ballot version.
__global__ __launch_bounds__(1024) void k_nms2(
    const float* __restrict__ boxes, const float* __restrict__ scores,
    const unsigned char* __restrict__ valid,
    const unsigned int* __restrict__ cnt, const unsigned long long* __restrict__ cand,
    float* __restrict__ out)
{
    __shared__ unsigned long long kb[2][2048];      // 32 KB double buffer (sort)
    __shared__ unsigned int lh32[NB2];              // 1 KB (cold path only)
    __shared__ int best;
    __shared__ unsigned int lpos;
    __shared__ float4 box4[512];                    // 8 KB
    __shared__ float  ar[512];                      // 2 KB
    __shared__ float  scs[512];                     // 2 KB
    __shared__ unsigned long long supT[512 * 9];    // 36 KB (+1 pad)
    __shared__ unsigned long long keepsh[8];
    __shared__ int pfx[9];

    int bc = blockIdx.x;
    int b  = bc / CC;
    int c  = bc % CC;
    int i  = threadIdx.x;
    const unsigned long long* cp = cand + (size_t)bc * CAP;

    int n = (int)cnt[bc];    // attempt count: may exceed CAP
    if (n < K_PRE || n > CAP) {
        // ---- cold rebuild: hist -> cut -> fresh gather (never on this data)
        unsigned long long* cpw = (unsigned long long*)cp;
        for (int t = i; t < NB2; t += 1024) lh32[t] = 0u;
        if (i == 0) { best = 0; lpos = 0u; }
        __syncthreads();
        for (int a = i; a < AA; a += 1024) {
            if (valid[b * AA + a]) {
                float sc = scores[((size_t)(b * AA + a)) * CC + c];
                if (sc > 0.05f) {
                    int bn = min((int)(sc * 256.0f), 255);
                    atomicAdd(&lh32[bn], 1u);
                }
            }
        }
        __syncthreads();
        if (i < NB2) {
            unsigned int s = 0;
            for (int j = i; j < NB2; ++j) s += lh32[j];   // suffix sum at i
            if (s >= K_PRE) atomicMax(&best, i);
        }
        __syncthreads();
        int cut = best;
        for (int a = i; a < AA; a += 1024) {
            if (valid[b * AA + a]) {
                float sc = scores[((size_t)(b * AA + a)) * CC + c];
                if (sc > 0.05f) {
                    int bn = min((int)(sc * 256.0f), 255);
                    if (bn >= cut) {
                        unsigned int p = atomicAdd(&lpos, 1u);
                        if (p < CAP)
                            cpw[p] = (((unsigned long long)__float_as_uint(sc)) << 32)
                                     | (unsigned long long)(~(unsigned int)a);
                    }
                }
            }
        }
        __syncthreads();   // this block's global writes visible block-wide
        n = (int)min(lpos, (unsigned int)CAP);
    }

    unsigned long long key;

    if (n <= 1024) {
        key = (i < n) ? cp[i] : 0ull;
        int p = 0;
        for (unsigned int k = 2; k <= 1024; k <<= 1) {
            bool up = ((i & k) == 0);
            for (unsigned int j = k >> 1; j > 0; j >>= 1) {
                unsigned long long other;
                if (j >= 64) {
                    kb[p][i] = key;
                    __syncthreads();
                    other = kb[p][i ^ j];
                    p ^= 1;                      // ping-pong: WAR-safe, 1 barrier/pass
                } else {
                    other = __shfl_xor(key, (int)j);
                }
                bool lower = ((i & j) == 0);
                bool keep_max = (lower == up);   // descending in "up" region
                bool mine_big = key > other;
                key = (keep_max == mine_big) ? key : other;
            }
        }
    } else {
        // 2048 fallback: 2 elements/thread (t=i and t=i+1024), hybrid passes
        unsigned long long kA = (i < n) ? cp[i] : 0ull;
        unsigned long long kB = (i + 1024 < n) ? cp[i + 1024] : 0ull;
        int tA = i, tB = i + 1024;
        int p = 0;
        for (unsigned int k = 2; k <= 2048; k <<= 1) {
            for (unsigned int j = k >> 1; j > 0; j >>= 1) {
                if (j == 1024) {
                    unsigned long long mx = (kA > kB) ? kA : kB;
                    unsigned long long mn = (kA > kB) ? kB : kA;
                    kA = mx; kB = mn;
                } else if (j >= 64) {
                    kb[p][tA] = kA; kb[p][tB] = kB;
                    __syncthreads();
                    unsigned long long oA = kb[p][tA ^ (int)j];
                    unsigned long long oB = kb[p][tB ^ (int)j];
                    p ^= 1;
                    { bool up = ((tA & k) == 0), lo = ((tA & j) == 0);
                      bool km = (lo == up), mb = kA > oA; kA = (km == mb) ? kA : oA; }
                    { bool up = ((tB & k) == 0), lo = ((tB & j) == 0);
                      bool km = (lo == up), mb = kB > oB; kB = (km == mb) ? kB : oB; }
                } else {
                    unsigned long long oA = __shfl_xor(kA, (int)j);
                    unsigned long long oB = __shfl_xor(kB, (int)j);
                    { bool up = ((tA & k) == 0), lo = ((tA & j) == 0);
                      bool km = (lo == up), mb = kA > oA; kA = (km == mb) ? kA : oA; }
                    { bool up = ((tB & k) == 0), lo = ((tB & j) == 0);
                      bool km = (lo == up), mb = kB > oB; kB = (km == mb) ? kB : oB; }
                }
            }
        }
        key = kA;   // element i (descending) lives in kA across threads
    }

    // ---- box gather into LDS ----
    if (i < 512) {
        bool v = (key != 0ull);
        scs[i] = v ? __uint_as_float((unsigned int)(key >> 32)) : -1.0f;
        int a = v ? (int)(~(unsigned int)key) : 0;
        float4 bb = make_float4(0.f, 0.f, 0.f, 0.f);
        if (v && i < K_PRE) bb = ((const float4*)boxes)[(size_t)b * AA + a];
        box4[i] = bb;
        ar[i] = (bb.z - bb.x) * (bb.w - bb.y);
    }
    __syncthreads();

    int nv = min(n, K_PRE);

    // ---- word-per-lane mask: 36 wave-uniform 64-row chunks over 16 waves --
    // Chunk ci covers iw (i-word) and rows j in [(iw+co)*64, +64); lane owns
    // row j, accumulates 64 bits (i = iw*64+k) in a register, one ds_write.
    {
        int wave = i >> 6;
        int lane = i & 63;
        for (int ci = wave; ci < 36; ci += 16) {
            // starts per iw: {0,8,15,21,26,30,33,35} (8-iw chunks per iw)
            int iw;
            if      (ci >= 35) iw = 7;
            else if (ci >= 33) iw = 6;
            else if (ci >= 30) iw = 5;
            else if (ci >= 26) iw = 4;
            else if (ci >= 21) iw = 3;
            else if (ci >= 15) iw = 2;
            else if (ci >=  8) iw = 1;
            else               iw = 0;
            int cst = (iw == 0) ? 0 : (iw == 1) ? 8 : (iw == 2) ? 15 :
                      (iw == 3) ? 21 : (iw == 4) ? 26 : (iw == 5) ? 30 :
                      (iw == 6) ? 33 : 35;
            int co  = ci - cst;
            int j   = (iw + co) * 64 + lane;
            bool have = j < nv;
            int js  = have ? j : 0;
            float4 bj = box4[js];
            float  ja = ar[js];
            int base = iw * 64;
            unsigned long long acc = 0ull;
            #pragma unroll 16
            for (int k = 0; k < 64; ++k) {
                float4 bi = box4[base + k];     // wave-uniform broadcast
                float  ia = ar[base + k];
                float ltx = fmaxf(bi.x, bj.x);
                float lty = fmaxf(bi.y, bj.y);
                float rbx = fminf(bi.z, bj.z);
                float rby = fminf(bi.w, bj.w);
                float wx = fmaxf(rbx - ltx, 0.0f);
                float wy = fmaxf(rby - lty, 0.0f);
                float inter = wx * wy;
                float den = fmaxf(ia + ja - inter, 1e-9f);
                float h   = 0.5f * den;          // exact (exponent decrement)
                float diff = inter - h;          // exact near boundary (Sterbenz)
                bool p;
                if (fabsf(diff) > h * 9.5367431640625e-07f) {
                    p = diff > 0.0f;             // provably == (inter/den > 0.5)
                } else {
                    p = (inter / den) > 0.5f;    // vanishing band: replay division
                }
                if (p) acc |= (1ull << k);
            }
            if (co == 0) acc &= (1ull << (j & 63)) - 1ull;   // diagonal: i<j only
            if (have) supT[j * 9 + iw] = acc;
        }
    }
    __syncthreads();

    // ---- exact greedy: word-blocked Gauss-Seidel, intra-word Jacobi ----
    if (i < 64) {
        int l = i;
        unsigned long long kept[8];
        #pragma unroll
        for (int w = 0; w < 8; ++w) {
            int j = w * 64 + l;
            bool vj = j < nv;
            bool ext = false;
            #pragma unroll
            for (int w2 = 0; w2 < 8; ++w2)
                if (w2 < w) ext = ext || (vj && (supT[j * 9 + w2] & kept[w2]) != 0ull);
            unsigned long long intra = vj ? supT[j * 9 + w] : 0ull;  // bits i<j only
            bool base = vj && !ext;
            unsigned long long kw = __ballot(base);
            for (int r = 0; r < 64; ++r) {                // depth <= 64 => exact
                bool k2 = base && ((intra & kw) == 0ull);
                unsigned long long nkw = __ballot(k2);
                if (nkw == kw) break;
                kw = nkw;
            }
            kept[w] = kw;
        }
        if (l < 8) keepsh[l] = kept[l];
    }
    __syncthreads();

    if (i == 0) {
        int s = 0;
        for (int w = 0; w < 8; ++w) { pfx[w] = s; s += __popcll(keepsh[w]); }
        pfx[8] = s;
    }
    __syncthreads();

    // ---- compaction: kept first (score order), then non-kept ----
    int total_kept = pfx[8];
    if (i < K_PRE) {
        int t = i;
        int w = t >> 6, bit = t & 63;
        unsigned long long kw = keepsh[w];
        bool kv = (kw >> bit) & 1ull;
        int kb2 = pfx[w] + __popcll(kw & ((bit == 0) ? 0ull : ((1ull << bit) - 1ull)));
        int p = kv ? kb2 : (total_kept + (t - kb2));
        if (p < MAX_DET) {
            float* o = out + ((size_t)bc * MAX_DET + p) * 5;
            if (kv) {
                float4 bb = box4[t];
                o[0] = bb.x; o[1] = bb.y; o[2] = bb.z; o[3] = bb.w; o[4] = scs[t];
            } else {
                o[0] = 0.f; o[1] = 0.f; o[2] = 0.f; o[3] = 0.f; o[4] = -1.0f;
            }
        }
    }
}

extern "C" void kernel_launch(void* const* d_in, const int* in_sizes, int n_in,
                              void* d_out, int out_size, void* d_ws, size_t ws_size,
                              hipStream_t stream)
{
    const float* deltas  = (const float*)d_in[0];
    const float* scores  = (const float*)d_in[1];
    const float* anchors = (const float*)d_in[2];
    const int*   ih      = (const int*)d_in[3];
    const int*   iw      = (const int*)d_in[4];
    float* out = (float*)d_out;

    char* w = (char*)d_ws;
    float*              boxes  = (float*)(w + OFF_BOXES);
    unsigned char*      valid  = (unsigned char*)(w + OFF_VALID);
    unsigned int*       cnt    = (unsigned int*)(w + OFF_CNT);
    unsigned long long* cand   = (unsigned long long*)(w + OFF_CAND);

    hipMemsetAsync(cnt, 0, BB * CC * sizeof(unsigned int), stream);
    k_fused<<<HB, 256, 0, stream>>>(deltas, anchors, scores, ih, iw,
                                    boxes, valid, cnt, cand);
    k_nms2<<<BB * CC, 1024, 0, stream>>>(boxes, scores, valid, cnt, cand, out);
}